// Round 3
// 1898.251 us; speedup vs baseline: 1.1876x; 1.1876x over previous
//
#include <hip/hip_runtime.h>

#define Bn 512
#define Tn 256
#define Fn 128
#define Hn 512
#define KIE 20   // 640/32 k-iters (encoder: [x|h], K=640)
#define KID 16   // 512/32 k-iters (decoder: h only, K=512)
#define NWG 256
#define RS 648   // A_lds row stride in ushorts (16B-aligned)

typedef __attribute__((ext_vector_type(8))) __bf16 bf16x8;
typedef __attribute__((ext_vector_type(4))) float floatx4;
typedef __attribute__((ext_vector_type(4))) unsigned uintx4;

__device__ __forceinline__ unsigned short f2bf_u16(float f) {
  union { float f; unsigned u; } v; v.f = f;
  unsigned r = v.u + 0x7FFFu + ((v.u >> 16) & 1u);   // RNE
  return (unsigned short)(r >> 16);
}

// fast sigmoid/tanh via v_exp_f32 + v_rcp_f32 (error ~1e-6, << bf16 rounding)
__device__ __forceinline__ float sigm(float x) {
  return __builtin_amdgcn_rcpf(1.f + __expf(-x));
}
__device__ __forceinline__ float ftanh(float x) {
  return 1.f - 2.f * __builtin_amdgcn_rcpf(1.f + __expf(2.f * x));
}

// ---- pack encoder weights [x|h] -> B-fragment order [nt][ki][lane][8] ----
__global__ void pack_enc_k(const float* __restrict__ Wih, const float* __restrict__ Whh,
                           unsigned short* __restrict__ Bpe) {
  int id = blockIdx.x;              // nt*KIE + ki
  int nt = id / KIE, ki = id % KIE;
  int l = threadIdx.x;
  int n = nt * 16 + (l & 15);
  int kb = ki * 32 + (l >> 4) * 8;
  __align__(16) unsigned short o[8];
#pragma unroll
  for (int j = 0; j < 8; ++j) {
    int k = kb + j;
    float v = (k < Fn) ? Wih[n * Fn + k] : Whh[n * Hn + (k - Fn)];
    o[j] = f2bf_u16(v);
  }
  *(uint4*)(Bpe + (size_t)(id * 64 + l) * 8) = *(uint4*)o;
}

// ---- pack decoder combined weights (W_hh + W_ih@Wo) -> fragment order ----
__global__ void pack_dec_k(const float* __restrict__ Wih, const float* __restrict__ Whh,
                           const float* __restrict__ Wo, unsigned short* __restrict__ Bpd) {
  int id = blockIdx.x;              // nt*KID + ki
  int nt = id / KID, ki = id % KID;
  int l = threadIdx.x;
  int n = nt * 16 + (l & 15);
  int kb = ki * 32 + (l >> 4) * 8;
  float acc[8];
#pragma unroll
  for (int j = 0; j < 8; ++j) acc[j] = Whh[n * Hn + kb + j];
  for (int f = 0; f < Fn; ++f) {
    float wf = Wih[n * Fn + f];
    const float* wo = Wo + f * Hn + kb;
#pragma unroll
    for (int j = 0; j < 8; ++j) acc[j] += wf * wo[j];
  }
  __align__(16) unsigned short o[8];
#pragma unroll
  for (int j = 0; j < 8; ++j) o[j] = f2bf_u16(acc[j]);
  *(uint4*)(Bpd + (size_t)(id * 64 + l) * 8) = *(uint4*)o;
}

// ---- pack Wo (for y = h@Wo.T) -> fragment order [ft][ki][lane][8] ----
__global__ void pack_wo_k(const float* __restrict__ Wo, unsigned short* __restrict__ Bpw) {
  int id = blockIdx.x;              // ft*KID + ki
  int ft = id / KID, ki = id % KID;
  int l = threadIdx.x;
  int f = ft * 16 + (l & 15);
  int kb = ki * 32 + (l >> 4) * 8;
  __align__(16) unsigned short o[8];
#pragma unroll
  for (int j = 0; j < 8; ++j) o[j] = f2bf_u16(Wo[f * Hn + kb + j]);
  *(uint4*)(Bpw + (size_t)(id * 64 + l) * 8) = *(uint4*)o;
}

// ---- biases: benc = eb_ih+eb_hh ; bdec = db_ih+db_hh + dW_ih@bo ----
__global__ void bias_k(const float* __restrict__ ebih, const float* __restrict__ ebhh,
                       const float* __restrict__ dbih, const float* __restrict__ dbhh,
                       const float* __restrict__ dWih, const float* __restrict__ bo,
                       float* __restrict__ benc, float* __restrict__ bdec) {
  int n = blockIdx.x * blockDim.x + threadIdx.x;  // 2048
  benc[n] = ebih[n] + ebhh[n];
  float a = dbih[n] + dbhh[n];
  for (int f = 0; f < Fn; ++f) a += dWih[n * Fn + f] * bo[f];
  bdec[n] = a;
}

// ---- pack x: ts[b][s][k] fp32 -> xp[s][b][k] bf16 ----
__global__ void pack_x_k(const float* __restrict__ ts, unsigned short* __restrict__ xp) {
  size_t i = (size_t)blockIdx.x * 256 + threadIdx.x;   // quad index
  int k4 = (int)(i & 31);
  size_t bs = i >> 5;
  int s = (int)(bs & 255);
  size_t b = bs >> 8;
  float4 v = *(const float4*)(ts + (i << 2));
  __align__(8) unsigned short o[4];
  o[0] = f2bf_u16(v.x); o[1] = f2bf_u16(v.y); o[2] = f2bf_u16(v.z); o[3] = f2bf_u16(v.w);
  *(unsigned long long*)(xp + ((size_t)s * Bn + b) * Fn + k4 * 4) = *(unsigned long long*)o;
}

// ---- init: zero Hg buffer 0 (512 KB) + both flag arrays + XCC sentinels ----
__global__ void init_k(unsigned long long* __restrict__ Hg0,
                       unsigned* __restrict__ flgA, unsigned* __restrict__ flgB,
                       unsigned* __restrict__ xcdP) {
  int i = blockIdx.x * 256 + threadIdx.x;   // 65536
  Hg0[i] = 0ULL;
  if (i < 8192) { flgA[i] = 0u; flgB[i] = 0u; }
  if (i < NWG) xcdP[i] = 0xFFu;             // sentinel (overlays out[0..255])
}

// Flag protocol: byte-identical to the proven baseline (sc1 / LLC, agent scope).
#define POLL(F, p) do { \
  if (l < 16) { \
    const unsigned* fp_ = (F) + (size_t)(mg * 16 + l) * 32; \
    while (__hip_atomic_load(fp_, __ATOMIC_RELAXED, __HIP_MEMORY_SCOPE_AGENT) < (unsigned)(p)) \
      __builtin_amdgcn_s_sleep(1); \
  } \
  __asm__ __volatile__("" ::: "memory"); \
} while (0)

#define SETF(F, p) do { if (tid == 0) \
  __hip_atomic_store((F) + (size_t)gid * 32, (unsigned)(p), __ATOMIC_RELAXED, __HIP_MEMORY_SCOPE_AGENT); \
} while (0)

// h loads: loc==1 -> sc0 (bypass L1, hit this XCD's shared L2); else baseline sc1.
#define STAGE_H(bb, OFF, curbuf) do { \
  const unsigned short* sp_ = Hg + (size_t)(curbuf) * (Bn * Hn) + (size_t)((bb) + eb) * Hn + ej * 16; \
  uintx4 t0_, t1_; \
  if (loc) { \
    asm volatile("global_load_dwordx4 %0, %2, off sc0\n\t" \
                 "global_load_dwordx4 %1, %2, off offset:16 sc0\n\t" \
                 "s_waitcnt vmcnt(0)" \
                 : "=&v"(t0_), "=&v"(t1_) : "v"(sp_) : "memory"); \
  } else { \
    const unsigned long long* src_ = (const unsigned long long*)sp_; \
    unsigned long long v0_ = __hip_atomic_load(src_ + 0, __ATOMIC_RELAXED, __HIP_MEMORY_SCOPE_AGENT); \
    unsigned long long v1_ = __hip_atomic_load(src_ + 1, __ATOMIC_RELAXED, __HIP_MEMORY_SCOPE_AGENT); \
    unsigned long long v2_ = __hip_atomic_load(src_ + 2, __ATOMIC_RELAXED, __HIP_MEMORY_SCOPE_AGENT); \
    unsigned long long v3_ = __hip_atomic_load(src_ + 3, __ATOMIC_RELAXED, __HIP_MEMORY_SCOPE_AGENT); \
    t0_[0] = (unsigned)v0_; t0_[1] = (unsigned)(v0_ >> 32); t0_[2] = (unsigned)v1_; t0_[3] = (unsigned)(v1_ >> 32); \
    t1_[0] = (unsigned)v2_; t1_[1] = (unsigned)(v2_ >> 32); t1_[2] = (unsigned)v3_; t1_[3] = (unsigned)(v3_ >> 32); \
  } \
  uintx4* dst_ = (uintx4*)&A_lds[eb * RS + (OFF) + ej * 16]; \
  dst_[0] = t0_; dst_[1] = t1_; \
} while (0)

#define STAGE_X(bb, s_) do { if (tid < 256) { \
  uint4 xv_ = *(const uint4*)(xp + ((size_t)(s_) * Bn + (bb) + (tid >> 4)) * Fn + (tid & 15) * 8); \
  *(uint4*)&A_lds[(tid >> 4) * RS + (tid & 15) * 8] = xv_; \
} } while (0)

#define MFMA_GATES(BR, KN) do { \
  floatx4 acc_ = {0.f, 0.f, 0.f, 0.f}; \
  const unsigned short* Ar_ = &A_lds[l15 * RS + q * 8]; \
  _Pragma("unroll") for (int k = 0; k < (KN); ++k) \
    acc_ = __builtin_amdgcn_mfma_f32_16x16x32_bf16(*(const bf16x8*)(Ar_ + k * 32), (BR)[k], acc_, 0, 0, 0); \
  _Pragma("unroll") for (int r = 0; r < 4; ++r) \
    gates_lds[g_][q * 4 + r][nsub * 16 + l15] = acc_[r]; \
} while (0)

#define MFMA_GATES_Y(BR, doY, bb, sd) do { \
  floatx4 acc_ = {0.f, 0.f, 0.f, 0.f}, accy_ = {0.f, 0.f, 0.f, 0.f}; \
  const unsigned short* Ar_ = &A_lds[l15 * RS + q * 8]; \
  _Pragma("unroll") for (int k = 0; k < KID; ++k) { \
    bf16x8 a_ = *(const bf16x8*)(Ar_ + k * 32); \
    acc_ = __builtin_amdgcn_mfma_f32_16x16x32_bf16(a_, (BR)[k], acc_, 0, 0, 0); \
    if (doY) accy_ = __builtin_amdgcn_mfma_f32_16x16x32_bf16( \
        a_, *(const bf16x8*)&Bw_lds[(k * 64 + l) * 8], accy_, 0, 0, 0); \
  } \
  _Pragma("unroll") for (int r = 0; r < 4; ++r) \
    gates_lds[g_][q * 4 + r][nsub * 16 + l15] = acc_[r]; \
  if (doY) { \
    _Pragma("unroll") for (int r = 0; r < 4; ++r) \
      __builtin_nontemporal_store(accy_[r] + bof, \
        out + ((size_t)((bb) + q * 4 + r) * Tn + (Tn - 1 - (sd))) * Fn + ns * 16 + l15); \
  } \
} while (0)

// h stores: loc==1 -> plain write-through (lands in XCD L2, the coherence
// point; drained by the pre-SETF __syncthreads vmcnt(0)); else baseline sc1.
#define EPI(cvar, BI, BF, BG, BO, bb, nxtbuf) do { \
  float gi_ = gates_lds[0][eb][ej] + (BI); \
  float gf_ = gates_lds[1][eb][ej] + (BF); \
  float gg_ = gates_lds[2][eb][ej] + (BG); \
  float go_ = gates_lds[3][eb][ej] + (BO); \
  cvar = sigm(gf_) * cvar + sigm(gi_) * ftanh(gg_); \
  float h_ = sigm(go_) * ftanh(cvar); \
  unsigned short hv_ = f2bf_u16(h_); \
  unsigned short* hp_ = Hg + (size_t)(nxtbuf) * (Bn * Hn) + (size_t)((bb) + eb) * Hn + j0 + ej; \
  if (loc) *hp_ = hv_; \
  else __hip_atomic_store(hp_, hv_, __ATOMIC_RELAXED, __HIP_MEMORY_SCOPE_AGENT); \
} while (0)

// ---- persistent LSTM enc-dec: 256 wgs x 512 thr, two 16-row streams/wg ----
// wg ids are relabeled so that, under round-robin block->XCD dispatch, each
// 16-wg group is XCD-local; the group VERIFIES this via published
// HW_REG_XCC_ID (bounded wait) and otherwise keeps the proven LLC protocol.
__global__ __launch_bounds__(512, 2) void lstm_persist(
    const unsigned short* __restrict__ xp,
    const unsigned short* __restrict__ Bpe,
    const unsigned short* __restrict__ Bpd,
    const unsigned short* __restrict__ Bpw,
    const float* __restrict__ benc,
    const float* __restrict__ bdec,
    const float* __restrict__ bo,
    unsigned short* __restrict__ Hg,   // [2][512][512] bf16
    unsigned* __restrict__ flgA,
    unsigned* __restrict__ flgB,
    unsigned* __restrict__ xcdPub,     // [256] published XCC ids (overlays out)
    float* __restrict__ out)           // [512][256][128] fp32
{
  const int wg = blockIdx.x;
  const int tid = threadIdx.x;
  const int w = tid >> 6, l = tid & 63;
  const int l15 = l & 15, q = l >> 4;
  const int g_ = w >> 1, nsub = w & 1;       // wave = (gate, 16-col subtile)
  const int eb = tid >> 5, ej = tid & 31;    // epilogue/staging (row, col)

  // bijective relabel assuming round-robin XCD dispatch: XCD = wg & 7
  const int grp = wg & 7, rank = wg >> 3;    // rank 0..31 within assumed XCD
  const int mg = grp * 2 + (rank >> 4);      // batch-block group 0..15
  const int ns = rank & 15;                  // column slice within group
  const int gid = mg * 16 + ns;              // logical flag slot
  const int b0 = mg * 32, j0 = ns * 32;
  const int nt = g_ * 32 + ns * 2 + nsub;

  __shared__ __align__(16) unsigned short A_lds[16 * RS];        // 20.7 KB
  __shared__ __align__(16) float gates_lds[4][16][34];           //  8.7 KB
  __shared__ __align__(16) unsigned short Bw_lds[KID * 64 * 8];  // 16.4 KB
  __shared__ int sh_asn[2];

  // ---- publish my XCC id; bounded group-local locality verification ----
  if (tid == 0) {
    unsigned x_;
    asm volatile("s_getreg_b32 %0, hwreg(HW_REG_XCC_ID)" : "=s"(x_));
    x_ &= 15u;
    sh_asn[1] = (int)x_;
    __hip_atomic_store(&xcdPub[wg], x_, __ATOMIC_RELAXED, __HIP_MEMORY_SCOPE_AGENT);
  }
  __syncthreads();
  const unsigned myx = (unsigned)sh_asn[1];
  if (tid < 64) {                            // wave 0 checks the 16 members
    int ok = 1;
    if (tid < 16) {
      const int phys = grp + 8 * ((mg & 1) * 16 + tid);   // member's physical wg
      unsigned v_ = 0xFFu;
      for (int it = 0; it < 32768; ++it) {   // bounded: cannot hang
        v_ = __hip_atomic_load(&xcdPub[phys], __ATOMIC_RELAXED, __HIP_MEMORY_SCOPE_AGENT);
        if (v_ != 0xFFu) break;
        __builtin_amdgcn_s_sleep(2);
      }
      ok = (v_ == myx) ? 1 : 0;              // timeout/garbage -> 0 -> fallback
    }
    int all_ = __all(ok) ? 1 : 0;
    if (tid == 0) sh_asn[0] = all_;
  }
  __syncthreads();
  const int loc = sh_asn[0];                 // group-uniform by construction

  // ---- preload B tiles (enc + dec) into registers: (20+16)*4 = 144 regs ----
  bf16x8 Bq[KIE], Bd[KID];
  {
    const bf16x8* p = (const bf16x8*)Bpe + (size_t)nt * (KIE * 64) + l;
#pragma unroll
    for (int k = 0; k < KIE; ++k) Bq[k] = p[k * 64];
  }
  {
    const bf16x8* p = (const bf16x8*)Bpd + (size_t)nt * (KID * 64) + l;
#pragma unroll
    for (int k = 0; k < KID; ++k) Bd[k] = p[k * 64];
  }
  // per-thread gate biases
  const float bie = benc[0 * Hn + j0 + ej], bfe = benc[1 * Hn + j0 + ej];
  const float bge = benc[2 * Hn + j0 + ej], boe = benc[3 * Hn + j0 + ej];
  const float bid = bdec[0 * Hn + j0 + ej], bfd = bdec[1 * Hn + j0 + ej];
  const float bgd = bdec[2 * Hn + j0 + ej], bod = bdec[3 * Hn + j0 + ej];

  if (ns < 8) { // constant Wo slice -> LDS, once
    const uint4* src = (const uint4*)(Bpw + (size_t)ns * (KID * 64 * 8));
    uint4* dst = (uint4*)Bw_lds;
    dst[tid * 2] = src[tid * 2];
    dst[tid * 2 + 1] = src[tid * 2 + 1];
  }
  const bool yA = (ns < 8) && (w == 0);
  const bool yB = (ns < 8) && (w == 4);
  float bof = 0.f;
  if (yA || yB) bof = bo[ns * 16 + l15];

  const int bbA = b0, bbB = b0 + 16;
  float cA = 0.f, cB = 0.f;

  __syncthreads();                   // Bw_lds staged

  // ================= encoder =================
  for (int s = 0; s < Tn; ++s) {
    const int cur = s & 1, nxt = cur ^ 1;
    POLL(flgA, s);
    STAGE_X(bbA, s);
    STAGE_H(bbA, Fn, cur);
    __syncthreads();                 // A staged; drains prev-iter epi-B stores
    SETF(flgB, s);
    MFMA_GATES(Bq, KIE);
    __syncthreads();                 // gates A ready; A_lds free
    POLL(flgB, s);
    STAGE_X(bbB, s);
    STAGE_H(bbB, Fn, cur);
    EPI(cA, bie, bfe, bge, boe, bbA, nxt);
    __syncthreads();                 // B staged; drains epi-A stores
    SETF(flgA, s + 1);
    MFMA_GATES(Bq, KIE);
    __syncthreads();                 // gates B ready
    EPI(cB, bie, bfe, bge, boe, bbB, nxt);
  }

  // ================= decoder =================
  cA = 0.f; cB = 0.f;                // reference restarts c at zero
  for (int sd = 0; sd < Tn; ++sd) {
    const int phg = Tn + sd;
    const int cur = phg & 1, nxt = cur ^ 1;
    POLL(flgA, phg);
    STAGE_H(bbA, 0, cur);
    __syncthreads();
    SETF(flgB, phg);
    MFMA_GATES_Y(Bd, yA, bbA, sd);
    __syncthreads();
    POLL(flgB, phg);
    STAGE_H(bbB, 0, cur);
    EPI(cA, bid, bfd, bgd, bod, bbA, nxt);
    __syncthreads();
    SETF(flgA, phg + 1);
    MFMA_GATES_Y(Bd, yB, bbB, sd);
    __syncthreads();
    EPI(cB, bid, bfd, bgd, bod, bbB, nxt);
  }
}

extern "C" void kernel_launch(void* const* d_in, const int* in_sizes, int n_in,
                              void* d_out, int out_size, void* d_ws, size_t ws_size,
                              hipStream_t stream) {
  const float* ts   = (const float*)d_in[0];
  const float* eWih = (const float*)d_in[1];
  const float* eWhh = (const float*)d_in[2];
  const float* ebih = (const float*)d_in[3];
  const float* ebhh = (const float*)d_in[4];
  const float* dWih = (const float*)d_in[5];
  const float* dWhh = (const float*)d_in[6];
  const float* dbih = (const float*)d_in[7];
  const float* dbhh = (const float*)d_in[8];
  const float* Wo   = (const float*)d_in[9];
  const float* bo   = (const float*)d_in[10];
  float* outp = (float*)d_out;

  char* ws = (char*)d_ws;
  unsigned short* Bpe  = (unsigned short*)(ws);                 // 2,621,440 B
  unsigned short* Bpd  = (unsigned short*)(ws + 2621440);       // 2,097,152 B
  unsigned short* Bpw  = (unsigned short*)(ws + 4718592);       //   131,072 B
  float*          benc = (float*)(ws + 4849664);                //     8,192 B
  float*          bdec = (float*)(ws + 4857856);                //     8,192 B
  unsigned short* Hg   = (unsigned short*)(ws + 4866048);       // 1,048,576 B
  unsigned*       flgA = (unsigned*)(ws + 5914624);             //    32,768 B
  unsigned*       flgB = (unsigned*)(ws + 5947392);             //    32,768 B
  unsigned short* xp   = (unsigned short*)(ws + 5980160);       // 16,777,216 B
  unsigned*       xcdP = (unsigned*)outp;   // scratch overlay; decoder rewrites
                                            // out[0..255] only at sd>=254,
                                            // strictly after all reads of it

  pack_enc_k<<<128 * KIE, 64, 0, stream>>>(eWih, eWhh, Bpe);
  pack_dec_k<<<128 * KID, 64, 0, stream>>>(dWih, dWhh, Wo, Bpd);
  pack_wo_k<<<8 * KID, 64, 0, stream>>>(Wo, Bpw);
  bias_k<<<8, 256, 0, stream>>>(ebih, ebhh, dbih, dbhh, dWih, bo, benc, bdec);
  pack_x_k<<<16384, 256, 0, stream>>>(ts, xp);
  init_k<<<256, 256, 0, stream>>>((unsigned long long*)Hg, flgA, flgB, xcdP);

  lstm_persist<<<NWG, 512, 0, stream>>>(xp, Bpe, Bpd, Bpw, benc, bdec, bo, Hg,
                                        flgA, flgB, xcdP, outp);
}